// Round 8
// baseline (162.090 us; speedup 1.0000x reference)
//
#include <hip/hip_runtime.h>

#define NT 64
#define NB 8192
#define NS 32
#define NF 16
#define DT 0.05f
#define FP_ITERS 3

typedef float f32x2 __attribute__((ext_vector_type(2)));
typedef float f32x4 __attribute__((ext_vector_type(4)));

// tanh(x) = 1 - 2/(1 + exp2(K x)), K = 2*log2(e). 6 VALU ops per pair.
__device__ __forceinline__ f32x2 tanh2(f32x2 x) {
    const float K = 2.8853900817779268f;
    float e0 = __builtin_amdgcn_exp2f(K * x[0]);
    float e1 = __builtin_amdgcn_exp2f(K * x[1]);
    float r0 = __builtin_amdgcn_rcpf(e0 + 1.0f);
    float r1 = __builtin_amdgcn_rcpf(e1 + 1.0f);
    f32x2 r;
    r[0] = fmaf(-2.0f, r0, 1.0f);
    r[1] = fmaf(-2.0f, r1, 1.0f);
    return r;
}

// R6 post-mortem: VGPR_Count=80 < ~127-float live set and VALU busy-cycles
// ~4x source instruction count -> asm "+v" value-pins did not survive SROA;
// W/U are spilled/rematerialized inside the hot loop. Fix: load W/U via
// inline-asm global_load_dwordx2 — an asm def cannot be rematerialized or
// scalarized; outputs MUST live in real VGPRs.
// R7 crash post-mortem: macro indexed addresses via (&A0 - &WA[0]), UB across
// arrays -> poison addresses -> GPU memory fault. Fixed: explicit index base
// parameter; early-clobber "=&v" so load dests can't alias later addr regs.
//
// Lane map: lane = b*16 + p; b in [0,4) = batch within wave, p in [0,16) =
// state pair. 4 batches/wave -> 2048 waves = 2/SIMD.
__global__ __launch_bounds__(256, 2) void rnes_kernel(
    const float* __restrict__ y0,
    const float* __restrict__ forces,
    const float* __restrict__ W,
    const float* __restrict__ U,
    const float* __restrict__ bias,
    float* __restrict__ out)
{
    const int lane = threadIdx.x & 63;
    const int wv   = threadIdx.x >> 6;
    const int b    = lane >> 4;
    const int p    = lane & 15;
    const int batch = blockIdx.x * 16 + wv * 4 + b;

    // One-time DPP direction probe (immune to row_ror receive-direction
    // ambiguity): after ror:1 this lane holds the p of the lane it received
    // from; rotations compose, so ror:j delivers lane (p + dir*j) & 15.
    const int got = __builtin_amdgcn_update_dpp(0, p, 0x121, 0xF, 0xF, true) & 15;
    const int dir = (got == ((p + 1) & 15)) ? 1 : 15;

    // Per-lane addresses of W row 2p, column-pair q, in rotation order.
    const float* aW[16];
#pragma unroll
    for (int j = 0; j < 16; ++j) {
        const int q = (p + dir * j) & 15;
        aW[j] = W + (2*p) * NS + 2*q;
    }

    // WA[j] = (W[2p][2q], W[2p][2q+1]); WB[j] = row 2p+1 via offset:128
    // (row stride 32 floats = 128 B; max addr 990*4+128+8 = 4096 B, in
    // bounds). Inline-asm defs -> guaranteed VGPR-resident.
    f32x2 WA[16], WB[16];
#define RNES_LOADW8(D, J0, OFS)                                                \
    asm volatile(                                                              \
        "global_load_dwordx2 %0, %8, off " OFS "\n\t"                          \
        "global_load_dwordx2 %1, %9, off " OFS "\n\t"                          \
        "global_load_dwordx2 %2, %10, off " OFS "\n\t"                         \
        "global_load_dwordx2 %3, %11, off " OFS "\n\t"                         \
        "global_load_dwordx2 %4, %12, off " OFS "\n\t"                         \
        "global_load_dwordx2 %5, %13, off " OFS "\n\t"                         \
        "global_load_dwordx2 %6, %14, off " OFS "\n\t"                         \
        "global_load_dwordx2 %7, %15, off " OFS "\n\t"                         \
        "s_waitcnt vmcnt(0)"                                                   \
        : "=&v"(D[(J0)+0]), "=&v"(D[(J0)+1]), "=&v"(D[(J0)+2]),                \
          "=&v"(D[(J0)+3]), "=&v"(D[(J0)+4]), "=&v"(D[(J0)+5]),                \
          "=&v"(D[(J0)+6]), "=&v"(D[(J0)+7])                                   \
        : "v"(aW[(J0)+0]), "v"(aW[(J0)+1]), "v"(aW[(J0)+2]), "v"(aW[(J0)+3]),  \
          "v"(aW[(J0)+4]), "v"(aW[(J0)+5]), "v"(aW[(J0)+6]), "v"(aW[(J0)+7]))
    RNES_LOADW8(WA, 0, "");
    RNES_LOADW8(WA, 8, "");
    RNES_LOADW8(WB, 0, "offset:128");
    RNES_LOADW8(WB, 8, "offset:128");
#undef RNES_LOADW8

    // U in natural order: UA[f] = (U[2p][2f], U[2p][2f+1]); UB = row 2p+1
    // (+64 B). One base address, immediate offsets 0..120.
    const float* aU = U + (2*p) * NF;
    f32x2 UA[8], UB[8];
    asm volatile(
        "global_load_dwordx2 %0,  %16, off\n\t"
        "global_load_dwordx2 %1,  %16, off offset:8\n\t"
        "global_load_dwordx2 %2,  %16, off offset:16\n\t"
        "global_load_dwordx2 %3,  %16, off offset:24\n\t"
        "global_load_dwordx2 %4,  %16, off offset:32\n\t"
        "global_load_dwordx2 %5,  %16, off offset:40\n\t"
        "global_load_dwordx2 %6,  %16, off offset:48\n\t"
        "global_load_dwordx2 %7,  %16, off offset:56\n\t"
        "global_load_dwordx2 %8,  %16, off offset:64\n\t"
        "global_load_dwordx2 %9,  %16, off offset:72\n\t"
        "global_load_dwordx2 %10, %16, off offset:80\n\t"
        "global_load_dwordx2 %11, %16, off offset:88\n\t"
        "global_load_dwordx2 %12, %16, off offset:96\n\t"
        "global_load_dwordx2 %13, %16, off offset:104\n\t"
        "global_load_dwordx2 %14, %16, off offset:112\n\t"
        "global_load_dwordx2 %15, %16, off offset:120\n\t"
        "s_waitcnt vmcnt(0)"
        : "=&v"(UA[0]), "=&v"(UA[1]), "=&v"(UA[2]), "=&v"(UA[3]),
          "=&v"(UA[4]), "=&v"(UA[5]), "=&v"(UA[6]), "=&v"(UA[7]),
          "=&v"(UB[0]), "=&v"(UB[1]), "=&v"(UB[2]), "=&v"(UB[3]),
          "=&v"(UB[4]), "=&v"(UB[5]), "=&v"(UB[6]), "=&v"(UB[7])
        : "v"(aU));

    const f32x2 b2 = *(const f32x2*)(bias + 2*p);

    // y_prev, out[0] = y0
    f32x2 yp = *(const f32x2*)(y0 + (size_t)batch * NS + 2*p);
    __builtin_nontemporal_store(yp, (f32x2*)(out + (size_t)batch * NS + 2*p));

    // register prefetch of forces[1]: broadcast f32x4 x4 per b-group.
    const size_t fstep = (size_t)NB * NF;
    const f32x4* fb = (const f32x4*)(forces + (size_t)batch * NF);
    f32x4 upf[4];
#pragma unroll
    for (int j = 0; j < 4; ++j)
        upf[j] = __builtin_nontemporal_load(&fb[(fstep >> 2) + j]);

    for (int k = 1; k < NT; ++k) {
        // fu = U u + b, packed: sA accumulates both halves of row 2p.
        f32x2 sA = (f32x2){0.f, 0.f}, sB = (f32x2){0.f, 0.f};
#pragma unroll
        for (int f = 0; f < 8; ++f) {
            f32x4 u4 = upf[f >> 1];
            f32x2 u2 = (f & 1) ? (f32x2){u4[2], u4[3]} : (f32x2){u4[0], u4[1]};
            sA = UA[f] * u2 + sA;
            sB = UB[f] * u2 + sB;
        }
        const float fu0 = b2[0] + sA[0] + sA[1];
        const float fu1 = b2[1] + sB[0] + sB[1];

        // prefetch next step's forces (in flight across all 3 iterations)
        {
            int kn = (k + 1 < NT) ? (k + 1) : (NT - 1);
#pragma unroll
            for (int j = 0; j < 4; ++j)
                upf[j] = __builtin_nontemporal_load(&fb[(size_t)kn * (fstep >> 2) + j]);
        }

        // fixed-point iterations, warm start y_prev. Pure-register: 15
        // INDEPENDENT row_ror:j hops (all read the original y pair), packed
        // FMA accumulation, no memory ops. (Verified R6 loop, unchanged.)
        f32x2 y = yp;
#pragma unroll
        for (int it = 0; it < FP_ITERS; ++it) {
            const int y0i = __float_as_int(y[0]);
            const int y1i = __float_as_int(y[1]);
            f32x2 accA = (f32x2){fu0, 0.f};
            f32x2 accB = (f32x2){fu1, 0.f};
            // j = 0: own pair, no hop
            accA = WA[0] * y + accA;
            accB = WB[0] * y + accB;
#define RNES_HOP(J)                                                            \
            {                                                                  \
                f32x2 yq;                                                      \
                yq[0] = __int_as_float(__builtin_amdgcn_update_dpp(            \
                    0, y0i, 0x120 + (J), 0xF, 0xF, true));                     \
                yq[1] = __int_as_float(__builtin_amdgcn_update_dpp(            \
                    0, y1i, 0x120 + (J), 0xF, 0xF, true));                     \
                accA = WA[J] * yq + accA;                                      \
                accB = WB[J] * yq + accB;                                      \
            }
            RNES_HOP(1)  RNES_HOP(2)  RNES_HOP(3)  RNES_HOP(4)
            RNES_HOP(5)  RNES_HOP(6)  RNES_HOP(7)  RNES_HOP(8)
            RNES_HOP(9)  RNES_HOP(10) RNES_HOP(11) RNES_HOP(12)
            RNES_HOP(13) RNES_HOP(14) RNES_HOP(15)
#undef RNES_HOP
            f32x2 zt;
            zt[0] = accA[0] + accA[1];
            zt[1] = accB[0] + accB[1];
            f32x2 t = tanh2(zt);
            y[0] = fmaf(DT, t[0], yp[0]);
            y[1] = fmaf(DT, t[1], yp[1]);
        }

        yp = y;
        __builtin_nontemporal_store(y, (f32x2*)(out + ((size_t)k * NB + batch) * NS + 2*p));
    }
}

extern "C" void kernel_launch(void* const* d_in, const int* in_sizes, int n_in,
                              void* d_out, int out_size, void* d_ws, size_t ws_size,
                              hipStream_t stream) {
    const float* y0     = (const float*)d_in[0];
    const float* forces = (const float*)d_in[1];
    const float* W      = (const float*)d_in[2];
    const float* U      = (const float*)d_in[3];
    const float* b      = (const float*)d_in[4];
    float* out = (float*)d_out;

    dim3 grid(NB / 16);   // 512 blocks x 4 waves x 4 batches = 8192
    dim3 block(256);
    rnes_kernel<<<grid, block, 0, stream>>>(y0, forces, W, U, b, out);
}